// Round 5
// baseline (586.768 us; speedup 1.0000x reference)
//
#include <hip/hip_runtime.h>

// SSIM (32,3,512,512) fp32, separable 11x11 Gaussian, sqrt-free rational form.
// v5 = v4 + readfirstlane bit-cast fix.
//   v4 lesson: __builtin_amdgcn_readfirstlane is int(int) -> passing a float
//   IMPLICITLY CONVERTED it to int, truncating every gaussian tap to 0
//   (SSIM==1 everywhere, absmax 0.99). Bit-cast through int instead.
// Structure (from v3/v4):
//   - block = 1 wave = 64 threads, owns a 64-col x 64-row output stripe
//   - private LDS row ring: 11 rows x 74 cols of (x1,x2) float2 (6.5 KB)
//   - __syncthreads() between ring publish and halo reads (v3 lesson: the
//     compiler reorders ds_read above ds_write even within one wave --
//     cross-lane deps are invisible to per-lane alias analysis)
//   - prefetch of row t+1 issued AFTER the barrier -> vmcnt wait lands one
//     full compute phase later
//   - outer 7-iter loop rolled; inner 11-step unroll gives static ring slots
//   - __launch_bounds__(64,4): <=128 VGPRs (v2 lesson: 236 MB scratch-spill
//     WRITE_SIZE at 64 VGPRs; watch WRITE_SIZE stays <5 MB)

#define IMG_H 512
#define IMG_W 512
#define N_IMGS 96                    // 32 batch * 3 channels
#define WAVE_W 64                    // output cols per wave
#define STRIPE 64                    // output rows per wave
#define HALO 5
#define KW 11
#define IN_COLS (WAVE_W + 2*HALO)    // 74
#define N_ROWT (IMG_H / STRIPE)      // 8
#define N_COLT (IMG_W / WAVE_W)      // 8
#define N_BLOCKS (N_IMGS * N_ROWT * N_COLT)   // 6144
#define T_MAX 77                     // 7*11 steps; t>=74 stage rows never used
#define TOTAL_PIX (32.0f * 3.0f * 512.0f * 512.0f)

__global__ __launch_bounds__(64, 4) void ssim_main(
    const float* __restrict__ img1, const float* __restrict__ img2,
    const float* __restrict__ window, float* __restrict__ out)
{
    __shared__ float2 ring[KW][IN_COLS];   // 11 x 74 x 8B = 6512 B

    const int tid = threadIdx.x;           // 0..63, one output column per lane

    // 1D gaussian, wave-uniform (SGPRs): g[k] = w[5][k] / sqrt(w[5][5]).
    // readfirstlane is int(int): bit-cast, do NOT pass float (v4 bug).
    float g[KW];
    {
        const float inv = rsqrtf(window[5*KW + 5]);
        #pragma unroll
        for (int k = 0; k < KW; ++k)
            g[k] = __int_as_float(
                __builtin_amdgcn_readfirstlane(
                    __float_as_int(window[5*KW + k] * inv)));
    }

    const int b   = blockIdx.x;
    const int img = b >> 6;                // 8x8 tiles per image
    const int rem = b & 63;
    const int ty  = rem >> 3;              // 0..7 row stripe
    const int tx  = rem & 7;               // 0..7 col stripe
    const int r0  = ty * STRIPE;
    const int x0  = tx * WAVE_W;

    const float* __restrict__ p1 = img1 + (size_t)img * (IMG_H * IMG_W);
    const float* __restrict__ p2 = img2 + (size_t)img * (IMG_H * IMG_W);

    // Staging columns: lane tid covers ring col tid (gx = x0-5+tid); lanes
    // 0..9 also cover ring col tid+64.
    const int  gx1  = x0 - HALO + tid;
    const bool c1ok = (unsigned)gx1 < IMG_W;
    const bool tail = tid < (IN_COLS - WAVE_W);     // lanes 0..9
    const int  gx2  = gx1 + WAVE_W;
    const bool c2ok = tail && ((unsigned)gx2 < IMG_W);

    // h-value register ring (5 signals x 11 slots) -- lives in VGPRs.
    float r_h1[KW], r_h2[KW], r_h11[KW], r_h22[KW], r_h12[KW];
    #pragma unroll
    for (int i = 0; i < KW; ++i) {
        r_h1[i] = 0.f; r_h2[i] = 0.f; r_h11[i] = 0.f; r_h22[i] = 0.f; r_h12[i] = 0.f;
    }

    const float C1 = 1e-4f;   // (0.01*1.0)^2
    const float C2 = 9e-4f;   // (0.03*1.0)^2
    float sum = 0.f;

    // Prologue: load input row t=0 (gy = r0-5) into staging registers.
    float sa = 0.f, sb = 0.f, sa2 = 0.f, sb2 = 0.f;
    {
        const int gy = r0 - HALO;
        if ((unsigned)gy < IMG_H) {
            const int base = gy * IMG_W;
            if (c1ok) { sa  = p1[base + gx1]; sb  = p2[base + gx1]; }
            if (c2ok) { sa2 = p1[base + gx2]; sb2 = p2[base + gx2]; }
        }
    }

    #pragma unroll 1
    for (int tb = 0; tb < T_MAX; tb += KW) {
        #pragma unroll
        for (int u = 0; u < KW; ++u) {       // t % 11 == u, static ring slots
            const int t = tb + u;

            // 1) Publish row t into ring slot u.
            ring[u][tid] = make_float2(sa, sb);
            if (tail) ring[u][tid + WAVE_W] = make_float2(sa2, sb2);

            // 2) Make the cross-lane writes visible (1-wave workgroup: cheap).
            __syncthreads();

            // 3) Issue global loads for row t+1 (waited next step).
            {
                const int gy = r0 - HALO + t + 1;
                sa = 0.f; sb = 0.f; sa2 = 0.f; sb2 = 0.f;
                if ((unsigned)gy < IMG_H) {
                    const int base = gy * IMG_W;
                    if (c1ok) { sa  = p1[base + gx1]; sb  = p2[base + gx1]; }
                    if (c2ok) { sa2 = p1[base + gx2]; sb2 = p2[base + gx2]; }
                }
            }

            // 4) Horizontal 11-tap conv at col x0+tid from ring slot u.
            float h1 = 0.f, h2 = 0.f, h11 = 0.f, h22 = 0.f, h12 = 0.f;
            #pragma unroll
            for (int k = 0; k < KW; ++k) {
                const float2 v = ring[u][tid + k];
                const float t1 = g[k] * v.x;
                const float t2 = g[k] * v.y;
                h1  += t1;
                h2  += t2;
                h11 += t1 * v.x;
                h22 += t2 * v.y;
                h12 += t1 * v.y;
            }
            r_h1[u] = h1; r_h2[u] = h2; r_h11[u] = h11; r_h22[u] = h22; r_h12[u] = h12;

            // 5) Vertical gather + SSIM for output row r0 + t - 10
            //    (uniform branch: t depends only on tb/u).
            if (t >= 2*HALO && t < 2*HALO + STRIPE) {
                float mu1 = 0.f, mu2 = 0.f, e11 = 0.f, e22 = 0.f, e12 = 0.f;
                #pragma unroll
                for (int m = 0; m < KW; ++m) {
                    const int slot = (u + 1 + m) % KW;  // compile-time index
                    mu1 += g[m] * r_h1[slot];
                    mu2 += g[m] * r_h2[slot];
                    e11 += g[m] * r_h11[slot];
                    e22 += g[m] * r_h22[slot];
                    e12 += g[m] * r_h12[slot];
                }
                const float mu1s = mu1 * mu1, mu2s = mu2 * mu2, mu12 = mu1 * mu2;
                const float s1  = fmaxf(e11 - mu1s, 0.f);
                const float s2  = fmaxf(e22 - mu2s, 0.f);
                const float s12 = e12 - mu12;
                const float num = (2.f * mu12 + C1) * (2.f * s12 + C2);
                const float den = (mu1s + mu2s + C1) * (s1 + s2 + C2);
                sum += num * __builtin_amdgcn_rcpf(den);
            }
        }
    }

    // Wave reduction -> one atomicAdd per block.
    #pragma unroll
    for (int off = 32; off > 0; off >>= 1)
        sum += __shfl_down(sum, off, 64);
    if (tid == 0)
        atomicAdd(out, sum * (1.0f / TOTAL_PIX));
}

extern "C" void kernel_launch(void* const* d_in, const int* in_sizes, int n_in,
                              void* d_out, int out_size, void* d_ws, size_t ws_size,
                              hipStream_t stream) {
    const float* img1   = (const float*)d_in[0];
    const float* img2   = (const float*)d_in[1];
    const float* window = (const float*)d_in[2];
    float* out = (float*)d_out;

    hipMemsetAsync(out, 0, sizeof(float), stream);
    ssim_main<<<N_BLOCKS, 64, 0, stream>>>(img1, img2, window, out);
}

// Round 6
// 329.040 us; speedup vs baseline: 1.7833x; 1.7833x over previous
//
#include <hip/hip_runtime.h>

// SSIM (32,3,512,512) fp32, separable 11x11 Gaussian, sqrt-free rational form.
// v6 = v5 + register-budget fix. THE spill mechanism (v2, v5):
//   __launch_bounds__(B, w)'s second arg sets amdgpu-waves-per-eu MINIMUM
//   with unbounded max -> the allocator keeps shrinking VGPRs toward 8
//   waves/EU (64 regs), ACCEPTING SPILLS (v5: 64 VGPRs + 405 MB scratch).
//   Fix: amdgpu_waves_per_eu(2,4) -> cap 256 regs (min 2 waves), and max 4
//   tells the allocator not to chase occupancy below ~128 regs.
// Structure (validated exact in v5, absmax 0.0):
//   - block = 1 wave = 64 threads, owns a 64-col x 64-row output stripe
//   - private LDS row ring: 11 rows x 74 cols of (x1,x2) float2 (6.5 KB)
//   - __syncthreads() between ring publish and halo reads (v3 race lesson)
//   - prefetch of row t+1 issued after the barrier
//   - outer 7-iter loop rolled; inner 11-step unroll -> static ring slots
//   - gaussian taps in SGPRs via bit-cast readfirstlane (v4 lesson: the
//     builtin is int(int) -- a raw float arg gets truncated to 0)

#define IMG_H 512
#define IMG_W 512
#define N_IMGS 96                    // 32 batch * 3 channels
#define WAVE_W 64                    // output cols per wave
#define STRIPE 64                    // output rows per wave
#define HALO 5
#define KW 11
#define IN_COLS (WAVE_W + 2*HALO)    // 74
#define N_ROWT (IMG_H / STRIPE)      // 8
#define N_COLT (IMG_W / WAVE_W)      // 8
#define N_BLOCKS (N_IMGS * N_ROWT * N_COLT)   // 6144
#define T_MAX 77                     // 7*11 steps; t=74..76 are drain no-ops
#define TOTAL_PIX (32.0f * 3.0f * 512.0f * 512.0f)

__global__ __launch_bounds__(64)
__attribute__((amdgpu_waves_per_eu(2, 4)))
void ssim_main(
    const float* __restrict__ img1, const float* __restrict__ img2,
    const float* __restrict__ window, float* __restrict__ out)
{
    __shared__ float2 ring[KW][IN_COLS];   // 11 x 74 x 8B = 6512 B

    const int tid = threadIdx.x;           // 0..63, one output column per lane

    // 1D gaussian, wave-uniform (SGPRs): g[k] = w[5][k] / sqrt(w[5][5]).
    float g[KW];
    {
        const float inv = rsqrtf(window[5*KW + 5]);
        #pragma unroll
        for (int k = 0; k < KW; ++k)
            g[k] = __int_as_float(
                __builtin_amdgcn_readfirstlane(
                    __float_as_int(window[5*KW + k] * inv)));
    }

    const int b   = blockIdx.x;
    const int img = b >> 6;                // 8x8 tiles per image
    const int rem = b & 63;
    const int ty  = rem >> 3;              // 0..7 row stripe
    const int tx  = rem & 7;               // 0..7 col stripe
    const int r0  = ty * STRIPE;
    const int x0  = tx * WAVE_W;

    const float* __restrict__ p1 = img1 + (size_t)img * (IMG_H * IMG_W);
    const float* __restrict__ p2 = img2 + (size_t)img * (IMG_H * IMG_W);

    // Staging columns: lane tid covers ring col tid (gx = x0-5+tid); lanes
    // 0..9 also cover ring col tid+64.
    const int  gx1  = x0 - HALO + tid;
    const bool c1ok = (unsigned)gx1 < IMG_W;
    const bool tail = tid < (IN_COLS - WAVE_W);     // lanes 0..9
    const int  gx2  = gx1 + WAVE_W;
    const bool c2ok = tail && ((unsigned)gx2 < IMG_W);

    // h-value register ring (5 signals x 11 slots) -- must stay in VGPRs.
    float r_h1[KW], r_h2[KW], r_h11[KW], r_h22[KW], r_h12[KW];
    #pragma unroll
    for (int i = 0; i < KW; ++i) {
        r_h1[i] = 0.f; r_h2[i] = 0.f; r_h11[i] = 0.f; r_h22[i] = 0.f; r_h12[i] = 0.f;
    }

    const float C1 = 1e-4f;   // (0.01*1.0)^2
    const float C2 = 9e-4f;   // (0.03*1.0)^2
    float sum = 0.f;

    // Prologue: load input row t=0 (gy = r0-5) into staging registers.
    float sa = 0.f, sb = 0.f, sa2 = 0.f, sb2 = 0.f;
    {
        const int gy = r0 - HALO;
        if ((unsigned)gy < IMG_H) {
            const int base = gy * IMG_W;
            if (c1ok) { sa  = p1[base + gx1]; sb  = p2[base + gx1]; }
            if (c2ok) { sa2 = p1[base + gx2]; sb2 = p2[base + gx2]; }
        }
    }

    #pragma unroll 1
    for (int tb = 0; tb < T_MAX; tb += KW) {
        #pragma unroll
        for (int u = 0; u < KW; ++u) {       // t % 11 == u, static ring slots
            const int t = tb + u;

            // 1) Publish row t into ring slot u.
            ring[u][tid] = make_float2(sa, sb);
            if (tail) ring[u][tid + WAVE_W] = make_float2(sa2, sb2);

            // 2) Cross-lane visibility (1-wave workgroup: ~just the waitcnt).
            __syncthreads();

            // 3) Issue global loads for row t+1 (waited at next ds_write).
            {
                const int gy = r0 - HALO + t + 1;
                sa = 0.f; sb = 0.f; sa2 = 0.f; sb2 = 0.f;
                if ((unsigned)gy < IMG_H) {
                    const int base = gy * IMG_W;
                    if (c1ok) { sa  = p1[base + gx1]; sb  = p2[base + gx1]; }
                    if (c2ok) { sa2 = p1[base + gx2]; sb2 = p2[base + gx2]; }
                }
            }

            // 4) Horizontal 11-tap conv at col x0+tid from ring slot u.
            float h1 = 0.f, h2 = 0.f, h11 = 0.f, h22 = 0.f, h12 = 0.f;
            #pragma unroll
            for (int k = 0; k < KW; ++k) {
                const float2 v = ring[u][tid + k];
                const float t1 = g[k] * v.x;
                const float t2 = g[k] * v.y;
                h1  += t1;
                h2  += t2;
                h11 += t1 * v.x;
                h22 += t2 * v.y;
                h12 += t1 * v.y;
            }
            r_h1[u] = h1; r_h2[u] = h2; r_h11[u] = h11; r_h22[u] = h22; r_h12[u] = h12;

            // 5) Vertical gather + SSIM for output row r0 + t - 10
            //    (uniform branch: t depends only on tb/u).
            if (t >= 2*HALO && t < 2*HALO + STRIPE) {
                float mu1 = 0.f, mu2 = 0.f, e11 = 0.f, e22 = 0.f, e12 = 0.f;
                #pragma unroll
                for (int m = 0; m < KW; ++m) {
                    const int slot = (u + 1 + m) % KW;  // compile-time index
                    mu1 += g[m] * r_h1[slot];
                    mu2 += g[m] * r_h2[slot];
                    e11 += g[m] * r_h11[slot];
                    e22 += g[m] * r_h22[slot];
                    e12 += g[m] * r_h12[slot];
                }
                const float mu1s = mu1 * mu1, mu2s = mu2 * mu2, mu12 = mu1 * mu2;
                const float s1  = fmaxf(e11 - mu1s, 0.f);
                const float s2  = fmaxf(e22 - mu2s, 0.f);
                const float s12 = e12 - mu12;
                const float num = (2.f * mu12 + C1) * (2.f * s12 + C2);
                const float den = (mu1s + mu2s + C1) * (s1 + s2 + C2);
                sum += num * __builtin_amdgcn_rcpf(den);
            }
        }
    }

    // Wave reduction -> one atomicAdd per block.
    #pragma unroll
    for (int off = 32; off > 0; off >>= 1)
        sum += __shfl_down(sum, off, 64);
    if (tid == 0)
        atomicAdd(out, sum * (1.0f / TOTAL_PIX));
}

extern "C" void kernel_launch(void* const* d_in, const int* in_sizes, int n_in,
                              void* d_out, int out_size, void* d_ws, size_t ws_size,
                              hipStream_t stream) {
    const float* img1   = (const float*)d_in[0];
    const float* img2   = (const float*)d_in[1];
    const float* window = (const float*)d_in[2];
    float* out = (float*)d_out;

    hipMemsetAsync(out, 0, sizeof(float), stream);
    ssim_main<<<N_BLOCKS, 64, 0, stream>>>(img1, img2, window, out);
}

// Round 7
// 319.694 us; speedup vs baseline: 1.8354x; 1.0292x over previous
//
#include <hip/hip_runtime.h>

// SSIM (32,3,512,512) fp32, separable 11x11 Gaussian, sqrt-free rational form.
// v7 = v6 + occupancy fix + atomic fan-out.
//   v6 post-mortem: spill gone (WRITE 192 B) but OccupancyPercent 28.5%
//   (2.3 waves/SIMD avg): waves_per_eu max=4 caps 16 waves/CU while the grid
//   needs 24/CU -> batch + ragged drain. Per-step serial chain (ds_write ->
//   lgkmcnt(0) -> ds_read ~120cyc -> 316 cyc VALU) can't be hidden by 2.3
//   waves -> latency-bound at 201 us vs ~62 us VALU floor.
//   Fix: amdgpu_waves_per_eu(2,6) -> budget 85 regs (natural use is 76, no
//   spill) and 24 waves/CU -> the WHOLE grid resident (LDS 24*6656=159.7KB
//   just fits 160KiB), zero drain.
//   Also: 6144 same-address atomicAdds burst at kernel end -> 256 bins in
//   d_ws + tiny reduce kernel.
// Carried lessons: waves_per_eu min caps regs / max stops spill-chasing (v2,
// v5, v6); barrier required even single-wave (v3); readfirstlane is int(int),
// bit-cast floats (v4).

#define IMG_H 512
#define IMG_W 512
#define N_IMGS 96                    // 32 batch * 3 channels
#define WAVE_W 64                    // output cols per wave
#define STRIPE 64                    // output rows per wave
#define HALO 5
#define KW 11
#define IN_COLS (WAVE_W + 2*HALO)    // 74
#define N_ROWT (IMG_H / STRIPE)      // 8
#define N_COLT (IMG_W / WAVE_W)      // 8
#define N_BLOCKS (N_IMGS * N_ROWT * N_COLT)   // 6144 = 24 blocks/CU, all resident
#define T_MAX 77                     // 7*11 steps; t=74..76 are drain no-ops
#define NBINS 256
#define TOTAL_PIX (32.0f * 3.0f * 512.0f * 512.0f)

__global__ __launch_bounds__(64)
__attribute__((amdgpu_waves_per_eu(2, 6)))
void ssim_main(
    const float* __restrict__ img1, const float* __restrict__ img2,
    const float* __restrict__ window, float* __restrict__ bins)
{
    __shared__ float2 ring[KW][IN_COLS];   // 11 x 74 x 8B = 6512 B

    const int tid = threadIdx.x;           // 0..63, one output column per lane

    // 1D gaussian, wave-uniform (SGPRs): g[k] = w[5][k] / sqrt(w[5][5]).
    float g[KW];
    {
        const float inv = rsqrtf(window[5*KW + 5]);
        #pragma unroll
        for (int k = 0; k < KW; ++k)
            g[k] = __int_as_float(
                __builtin_amdgcn_readfirstlane(
                    __float_as_int(window[5*KW + k] * inv)));
    }

    const int b   = blockIdx.x;
    const int img = b >> 6;                // 8x8 tiles per image
    const int rem = b & 63;
    const int ty  = rem >> 3;              // 0..7 row stripe
    const int tx  = rem & 7;               // 0..7 col stripe
    const int r0  = ty * STRIPE;
    const int x0  = tx * WAVE_W;

    const float* __restrict__ p1 = img1 + (size_t)img * (IMG_H * IMG_W);
    const float* __restrict__ p2 = img2 + (size_t)img * (IMG_H * IMG_W);

    // Staging columns: lane tid covers ring col tid (gx = x0-5+tid); lanes
    // 0..9 also cover ring col tid+64.
    const int  gx1  = x0 - HALO + tid;
    const bool c1ok = (unsigned)gx1 < IMG_W;
    const bool tail = tid < (IN_COLS - WAVE_W);     // lanes 0..9
    const int  gx2  = gx1 + WAVE_W;
    const bool c2ok = tail && ((unsigned)gx2 < IMG_W);

    // h-value register ring (5 signals x 11 slots) -- stays in VGPRs.
    float r_h1[KW], r_h2[KW], r_h11[KW], r_h22[KW], r_h12[KW];
    #pragma unroll
    for (int i = 0; i < KW; ++i) {
        r_h1[i] = 0.f; r_h2[i] = 0.f; r_h11[i] = 0.f; r_h22[i] = 0.f; r_h12[i] = 0.f;
    }

    const float C1 = 1e-4f;   // (0.01*1.0)^2
    const float C2 = 9e-4f;   // (0.03*1.0)^2
    float sum = 0.f;

    // Prologue: load input row t=0 (gy = r0-5) into staging registers.
    float sa = 0.f, sb = 0.f, sa2 = 0.f, sb2 = 0.f;
    {
        const int gy = r0 - HALO;
        if ((unsigned)gy < IMG_H) {
            const int base = gy * IMG_W;
            if (c1ok) { sa  = p1[base + gx1]; sb  = p2[base + gx1]; }
            if (c2ok) { sa2 = p1[base + gx2]; sb2 = p2[base + gx2]; }
        }
    }

    #pragma unroll 1
    for (int tb = 0; tb < T_MAX; tb += KW) {
        #pragma unroll
        for (int u = 0; u < KW; ++u) {       // t % 11 == u, static ring slots
            const int t = tb + u;

            // 1) Publish row t into ring slot u.
            ring[u][tid] = make_float2(sa, sb);
            if (tail) ring[u][tid + WAVE_W] = make_float2(sa2, sb2);

            // 2) Cross-lane visibility (1-wave workgroup: ~just the waitcnt).
            __syncthreads();

            // 3) Issue global loads for row t+1 (waited at next ds_write).
            {
                const int gy = r0 - HALO + t + 1;
                sa = 0.f; sb = 0.f; sa2 = 0.f; sb2 = 0.f;
                if ((unsigned)gy < IMG_H) {
                    const int base = gy * IMG_W;
                    if (c1ok) { sa  = p1[base + gx1]; sb  = p2[base + gx1]; }
                    if (c2ok) { sa2 = p1[base + gx2]; sb2 = p2[base + gx2]; }
                }
            }

            // 4) Horizontal 11-tap conv at col x0+tid from ring slot u.
            float h1 = 0.f, h2 = 0.f, h11 = 0.f, h22 = 0.f, h12 = 0.f;
            #pragma unroll
            for (int k = 0; k < KW; ++k) {
                const float2 v = ring[u][tid + k];
                const float t1 = g[k] * v.x;
                const float t2 = g[k] * v.y;
                h1  += t1;
                h2  += t2;
                h11 += t1 * v.x;
                h22 += t2 * v.y;
                h12 += t1 * v.y;
            }
            r_h1[u] = h1; r_h2[u] = h2; r_h11[u] = h11; r_h22[u] = h22; r_h12[u] = h12;

            // 5) Vertical gather + SSIM for output row r0 + t - 10
            //    (uniform branch: t depends only on tb/u).
            if (t >= 2*HALO && t < 2*HALO + STRIPE) {
                float mu1 = 0.f, mu2 = 0.f, e11 = 0.f, e22 = 0.f, e12 = 0.f;
                #pragma unroll
                for (int m = 0; m < KW; ++m) {
                    const int slot = (u + 1 + m) % KW;  // compile-time index
                    mu1 += g[m] * r_h1[slot];
                    mu2 += g[m] * r_h2[slot];
                    e11 += g[m] * r_h11[slot];
                    e22 += g[m] * r_h22[slot];
                    e12 += g[m] * r_h12[slot];
                }
                const float mu1s = mu1 * mu1, mu2s = mu2 * mu2, mu12 = mu1 * mu2;
                const float s1  = fmaxf(e11 - mu1s, 0.f);
                const float s2  = fmaxf(e22 - mu2s, 0.f);
                const float s12 = e12 - mu12;
                const float num = (2.f * mu12 + C1) * (2.f * s12 + C2);
                const float den = (mu1s + mu2s + C1) * (s1 + s2 + C2);
                sum += num * __builtin_amdgcn_rcpf(den);
            }
        }
    }

    // Wave reduction -> one atomicAdd per block, fanned over 256 bins.
    #pragma unroll
    for (int off = 32; off > 0; off >>= 1)
        sum += __shfl_down(sum, off, 64);
    if (tid == 0)
        atomicAdd(&bins[b & (NBINS - 1)], sum);
}

__global__ __launch_bounds__(64) void ssim_final(
    const float* __restrict__ bins, float* __restrict__ out)
{
    const int tid = threadIdx.x;
    float s = 0.f;
    #pragma unroll
    for (int i = 0; i < NBINS / 64; ++i) s += bins[tid + i * 64];
    #pragma unroll
    for (int off = 32; off > 0; off >>= 1)
        s += __shfl_down(s, off, 64);
    if (tid == 0) out[0] = s * (1.0f / TOTAL_PIX);
}

extern "C" void kernel_launch(void* const* d_in, const int* in_sizes, int n_in,
                              void* d_out, int out_size, void* d_ws, size_t ws_size,
                              hipStream_t stream) {
    const float* img1   = (const float*)d_in[0];
    const float* img2   = (const float*)d_in[1];
    const float* window = (const float*)d_in[2];
    float* bins = (float*)d_ws;
    float* out  = (float*)d_out;

    hipMemsetAsync(bins, 0, NBINS * sizeof(float), stream);
    ssim_main<<<N_BLOCKS, 64, 0, stream>>>(img1, img2, window, bins);
    ssim_final<<<1, 64, 0, stream>>>(bins, out);
}